// Round 1
// baseline (5332.238 us; speedup 1.0000x reference)
//
#include <hip/hip_runtime.h>
#include <math.h>

#define BATCH  2
#define SEQ    2048
#define NHEAD  16
#define DMODEL 2048
#define DCKV   512
#define DCQ    1024
#define DHEAD  128
#define DROPE  64

// ---------------------------------------------------------------------------
// Generic fp32 GEMM: C[M,N] = A[M,K] @ B[K,N], row-major.
// 128x128 tile, K-step 8, 256 threads, 8x8 register blocking.
// M must be a multiple of 128; K a multiple of 8; N a multiple of 4 (N<128 ok).
// ---------------------------------------------------------------------------
__global__ __launch_bounds__(256) void gemm_f32(const float* __restrict__ A,
                                                const float* __restrict__ Bm,
                                                float* __restrict__ C,
                                                int M, int N, int K)
{
    __shared__ float As[8][128];   // transposed: As[k][m]
    __shared__ float Bs[8][128];   // Bs[k][n]

    const int tid = threadIdx.x;
    const int m0  = blockIdx.y * 128;
    const int n0  = blockIdx.x * 128;
    const int tx  = tid & 15;        // 0..15 -> col group
    const int ty  = tid >> 4;        // 0..15 -> row group
    const int arow = tid >> 1;       // 0..127
    const int akk  = (tid & 1) * 4;  // 0 or 4
    const int brow = tid >> 5;       // 0..7
    const int bn   = (tid & 31) * 4; // 0..124

    const float* Aptr = A + (size_t)(m0 + arow) * K + akk;
    const float* Bptr = Bm + (size_t)brow * N + (n0 + bn);
    const bool   bok  = (n0 + bn) < N;

    float acc[8][8];
#pragma unroll
    for (int i = 0; i < 8; ++i)
#pragma unroll
        for (int j = 0; j < 8; ++j) acc[i][j] = 0.f;

    for (int kt = 0; kt < K; kt += 8) {
        float4 av = *(const float4*)Aptr;
        float4 bv = make_float4(0.f, 0.f, 0.f, 0.f);
        if (bok) bv = *(const float4*)Bptr;
        Aptr += 8;
        Bptr += (size_t)8 * N;

        __syncthreads();   // previous compute done before overwriting LDS
        As[akk + 0][arow] = av.x;
        As[akk + 1][arow] = av.y;
        As[akk + 2][arow] = av.z;
        As[akk + 3][arow] = av.w;
        *(float4*)&Bs[brow][bn] = bv;
        __syncthreads();

#pragma unroll
        for (int kk = 0; kk < 8; ++kk) {
            float4 a0 = *(const float4*)&As[kk][ty * 4];
            float4 a1 = *(const float4*)&As[kk][64 + ty * 4];
            float4 b0 = *(const float4*)&Bs[kk][tx * 4];
            float4 b1 = *(const float4*)&Bs[kk][64 + tx * 4];
            float a[8] = {a0.x, a0.y, a0.z, a0.w, a1.x, a1.y, a1.z, a1.w};
            float b[8] = {b0.x, b0.y, b0.z, b0.w, b1.x, b1.y, b1.z, b1.w};
#pragma unroll
            for (int i = 0; i < 8; ++i)
#pragma unroll
                for (int j = 0; j < 8; ++j) acc[i][j] += a[i] * b[j];
        }
    }

#pragma unroll
    for (int i = 0; i < 8; ++i) {
        const int mr = m0 + ty * 4 + (i & 3) + ((i >> 2) << 6);
        float* crow = C + (size_t)mr * N + n0;
        float4 c0 = make_float4(acc[i][0], acc[i][1], acc[i][2], acc[i][3]);
        float4 c1 = make_float4(acc[i][4], acc[i][5], acc[i][6], acc[i][7]);
        if (n0 + tx * 4 < N)      *(float4*)&crow[tx * 4]      = c0;
        if (n0 + 64 + tx * 4 < N) *(float4*)&crow[64 + tx * 4] = c1;
    }
}

// ---------------------------------------------------------------------------
// pope: in-place softplus + rotation on [B*S, hcols*64] buffer.
// pair (j, j+32) within each 64-wide head chunk shares angle j.
// ---------------------------------------------------------------------------
__device__ __forceinline__ float softplusf(float v)
{
    if (v > 20.f) return v;
    return log1pf(__expf(v));
}

__global__ __launch_bounds__(256) void pope_kernel(float* __restrict__ data,
                                                   const float* __restrict__ delta,
                                                   int hcols)
{
    const int idx   = blockIdx.x * 256 + threadIdx.x;
    const int total = BATCH * SEQ * hcols * 32;
    if (idx >= total) return;
    const int j     = idx & 31;
    const int h     = (idx >> 5) % hcols;
    const int rowid = idx / (32 * hcols);
    const int s     = rowid % SEQ;

    // theta_j = BASE^(-2j/64) = exp(-(2j/64) * ln(10000))
    const float theta = __expf(-(2.0f * (float)j) * (9.210340371976184f / 64.0f));
    const float ang   = (float)s * theta + delta[j];
    float sn, cs;
    sincosf(ang, &sn, &cs);

    float* row = data + (size_t)rowid * (hcols * 64) + h * 64;
    const float mu1 = softplusf(row[j]);
    const float mu2 = softplusf(row[j + 32]);
    row[j]      = mu1 * cs - mu2 * sn;
    row[j + 32] = mu1 * sn + mu2 * cs;
}

// ---------------------------------------------------------------------------
// Causal flash attention, fp32.
// grid: (SEQ/64, BATCH*NHEAD), block 256 = 4 waves.
// wave w owns q-rows w*16..w*16+15; lane = (rr, c): rr = row-in-wave, c = one
// of 4 48-dim slices of the 192-dim q/k vectors (also one of 4 32-dim slices
// of the 128-dim v/out). Butterfly shfl_xor(16/32) completes the dot product.
// K tile [32][192] (2-way bank aliasing only); V tile staggered: slice c of
// row k lives at Vs[k][c*36 .. c*36+31]  -> 4 distinct bank quads, no conflict.
// ---------------------------------------------------------------------------
__global__ __launch_bounds__(256) void attn_f32(const float* __restrict__ qc,
                                                const float* __restrict__ qr,
                                                const float* __restrict__ kc,
                                                const float* __restrict__ kr,
                                                const float* __restrict__ vv,
                                                float* __restrict__ ao)
{
    __shared__ float Ks[32][192];
    __shared__ float Vs[32][144];

    const int q0   = blockIdx.x * 64;
    const int bh   = blockIdx.y;
    const int b    = bh >> 4;
    const int h    = bh & 15;
    const int tid  = threadIdx.x;
    const int lane = tid & 63;
    const int wave = tid >> 6;
    const int rr   = lane & 15;
    const int c    = lane >> 4;          // 0..3
    const int row  = wave * 16 + rr;     // 0..63
    const int sq   = q0 + row;           // global query index
    const float scale = 0.07216878365f;  // 1/sqrt(192)

    // ---- load this lane's q slice (48 dims) into registers -----------------
    const size_t qcbase = ((size_t)(b * SEQ + sq)) * (NHEAD * DHEAD) + h * DHEAD;
    const size_t qrbase = ((size_t)(b * SEQ + sq)) * (NHEAD * DROPE) + h * DROPE;
    float4 qv[12];
#pragma unroll
    for (int jj = 0; jj < 12; ++jj) {
        const int g = c * 48 + jj * 4;
        qv[jj] = (g < DHEAD) ? *(const float4*)&qc[qcbase + g]
                             : *(const float4*)&qr[qrbase + (g - DHEAD)];
    }

    float  m    = -INFINITY;
    float  lsum = 0.f;
    float4 acc4[8];
#pragma unroll
    for (int j = 0; j < 8; ++j) acc4[j] = make_float4(0.f, 0.f, 0.f, 0.f);

    const int kend = q0 + 64;   // exclusive bound on needed k (<= SEQ)

    for (int k0 = 0; k0 < kend; k0 += 32) {
        __syncthreads();  // previous tile's compute done

        // ---- stage K tile: 32 rows x 192 (128 from kc, 64 from kr) --------
#pragma unroll
        for (int it = 0; it < 6; ++it) {
            const int idx = tid + it * 256;          // 0..1535
            const int k   = idx / 48;
            const int g   = (idx % 48) * 4;
            const size_t srow = (size_t)(b * SEQ + k0 + k);
            float4 v;
            if (g < DHEAD) v = *(const float4*)&kc[srow * (NHEAD * DHEAD) + h * DHEAD + g];
            else           v = *(const float4*)&kr[srow * DROPE + (g - DHEAD)];
            *(float4*)&Ks[k][g] = v;
        }
        // ---- stage V tile: 32 rows x 128, staggered layout ----------------
#pragma unroll
        for (int it = 0; it < 4; ++it) {
            const int idx = tid + it * 256;          // 0..1023
            const int k   = idx >> 5;
            const int j   = idx & 31;                // float4 index in row
            float4 v = *(const float4*)&vv[(size_t)(b * SEQ + k0 + k) * (NHEAD * DHEAD)
                                           + h * DHEAD + j * 4];
            *(float4*)&Vs[k][(j >> 3) * 36 + (j & 7) * 4] = v;
        }
        __syncthreads();

        // ---- scores: 32 per row, spread over 4 lanes then reduced ---------
        float p[32];
#pragma unroll
        for (int kk = 0; kk < 32; ++kk) {
            const float4* krow = (const float4*)&Ks[kk][c * 48];
            float s0 = 0.f, s1 = 0.f, s2 = 0.f, s3 = 0.f;
#pragma unroll
            for (int jj = 0; jj < 12; ++jj) {
                const float4 kv = krow[jj];
                s0 += qv[jj].x * kv.x;
                s1 += qv[jj].y * kv.y;
                s2 += qv[jj].z * kv.z;
                s3 += qv[jj].w * kv.w;
            }
            float sum = (s0 + s1) + (s2 + s3);
            sum += __shfl_xor(sum, 16);
            sum += __shfl_xor(sum, 32);
            const int kg = k0 + kk;
            p[kk] = (kg <= sq) ? sum * scale : -3.0e38f;
        }

        // ---- online softmax ----------------------------------------------
        float tmax = p[0];
#pragma unroll
        for (int kk = 1; kk < 32; ++kk) tmax = fmaxf(tmax, p[kk]);
        const float mnew  = fmaxf(m, tmax);
        const float alpha = __expf(m - mnew);   // m=-inf only on first tile; mnew finite
        float psum = 0.f;
#pragma unroll
        for (int kk = 0; kk < 32; ++kk) {
            p[kk] = __expf(p[kk] - mnew);
            psum += p[kk];
        }
        lsum = lsum * alpha + psum;
        m = mnew;
#pragma unroll
        for (int j = 0; j < 8; ++j) {
            acc4[j].x *= alpha; acc4[j].y *= alpha;
            acc4[j].z *= alpha; acc4[j].w *= alpha;
        }

        // ---- PV: out slice (32 dims) for this lane ------------------------
#pragma unroll
        for (int kk = 0; kk < 32; ++kk) {
            const float pk = p[kk];
            const float4* vrow = (const float4*)&Vs[kk][c * 36];
#pragma unroll
            for (int j = 0; j < 8; ++j) {
                const float4 v = vrow[j];
                acc4[j].x += pk * v.x;
                acc4[j].y += pk * v.y;
                acc4[j].z += pk * v.z;
                acc4[j].w += pk * v.w;
            }
        }
    }

    // ---- epilogue ---------------------------------------------------------
    const float inv = 1.0f / lsum;
    float4* dst = (float4*)&ao[((size_t)(b * SEQ) + sq) * (NHEAD * DHEAD) + h * DHEAD + c * 32];
#pragma unroll
    for (int j = 0; j < 8; ++j) {
        float4 o;
        o.x = acc4[j].x * inv;
        o.y = acc4[j].y * inv;
        o.z = acc4[j].z * inv;
        o.w = acc4[j].w * inv;
        dst[j] = o;
    }
}

// ---------------------------------------------------------------------------
// Workspace map (floats). ao overlaps c_kv+c_q (dead by attention time).
//   [0        , 8388608 )  c_kv (first 2097152) + c_q (next 4194304) / later ao
//   [8388608  , 16777216)  key_c   [4096,2048]
//   [16777216 , 25165824)  value   [4096,2048]
//   [25165824 , 33554432)  query_c [4096,2048]
//   [33554432 , 37748736)  query_r [4096,1024]  (=[B,S,H,64])
//   [37748736 , 38010880)  key_r   [4096,64]
// total 38,010,880 floats = 152 MB
// ---------------------------------------------------------------------------
extern "C" void kernel_launch(void* const* d_in, const int* in_sizes, int n_in,
                              void* d_out, int out_size, void* d_ws, size_t ws_size,
                              hipStream_t stream)
{
    const float* x     = (const float*)d_in[0];
    const float* w_dkv = (const float*)d_in[1];
    const float* w_uk  = (const float*)d_in[2];
    const float* w_uv  = (const float*)d_in[3];
    const float* w_dq  = (const float*)d_in[4];
    const float* w_uq  = (const float*)d_in[5];
    const float* w_qr  = (const float*)d_in[6];
    const float* w_kr  = (const float*)d_in[7];
    const float* w_out = (const float*)d_in[8];
    const float* delta = (const float*)d_in[9];
    float* out = (float*)d_out;
    float* ws  = (float*)d_ws;

    const int M = BATCH * SEQ;                 // 4096
    float* c_kv = ws;                          // 4096x512
    float* c_q  = ws + 2097152;                // 4096x1024
    float* ao   = ws;                          // 4096x2048 (overlaps dead c_kv/c_q)
    float* kcb  = ws + 8388608;
    float* vvb  = ws + 16777216;
    float* qcb  = ws + 25165824;
    float* qrb  = ws + 33554432;
    float* krb  = ws + 37748736;

    dim3 blk(256);

    gemm_f32<<<dim3(DCKV / 128, M / 128), blk, 0, stream>>>(x, w_dkv, c_kv, M, DCKV, DMODEL);
    gemm_f32<<<dim3(DCQ / 128, M / 128), blk, 0, stream>>>(x, w_dq, c_q, M, DCQ, DMODEL);
    gemm_f32<<<dim3(1, M / 128), blk, 0, stream>>>(x, w_kr, krb, M, DROPE, DMODEL);
    gemm_f32<<<dim3(2048 / 128, M / 128), blk, 0, stream>>>(c_kv, w_uk, kcb, M, NHEAD * DHEAD, DCKV);
    gemm_f32<<<dim3(2048 / 128, M / 128), blk, 0, stream>>>(c_kv, w_uv, vvb, M, NHEAD * DHEAD, DCKV);
    gemm_f32<<<dim3(2048 / 128, M / 128), blk, 0, stream>>>(c_q, w_uq, qcb, M, NHEAD * DHEAD, DCQ);
    gemm_f32<<<dim3(1024 / 128, M / 128), blk, 0, stream>>>(c_q, w_qr, qrb, M, NHEAD * DROPE, DCQ);

    pope_kernel<<<dim3((M * NHEAD * 32 + 255) / 256), blk, 0, stream>>>(qrb, delta, NHEAD);
    pope_kernel<<<dim3((M * 32 + 255) / 256), blk, 0, stream>>>(krb, delta, 1);

    attn_f32<<<dim3(SEQ / 64, BATCH * NHEAD), blk, 0, stream>>>(qcb, qrb, kcb, krb, vvb, ao);

    gemm_f32<<<dim3(2048 / 128, M / 128), blk, 0, stream>>>(ao, w_out, out, M, DMODEL, NHEAD * DHEAD);
}

// Round 3
// 1286.729 us; speedup vs baseline: 4.1440x; 4.1440x over previous
//
#include <hip/hip_runtime.h>
#include <math.h>

#define BATCH  2
#define SEQ    2048
#define NHEAD  16
#define DMODEL 2048
#define DCKV   512
#define DCQ    1024
#define DHEAD  128
#define DROPE  64

typedef unsigned short u16;
typedef __attribute__((ext_vector_type(8))) short bf16x8;
typedef __attribute__((ext_vector_type(4))) float f32x4;

__device__ __forceinline__ u16 f2bf(float f) {           // RNE
    union { float f; unsigned u; } v; v.f = f;
    unsigned r = v.u + 0x7FFFu + ((v.u >> 16) & 1u);
    return (u16)(r >> 16);
}
__device__ __forceinline__ float bf2f(u16 h) {
    union { unsigned u; float f; } v; v.u = ((unsigned)h) << 16;
    return v.f;
}

// ---------------------------------------------------------------------------
// transpose fp32 [R][C] -> fp32 [C][R].  R,C multiples of 64.
// grid (C/64, R/64), 256 thr.
// ---------------------------------------------------------------------------
__global__ __launch_bounds__(256) void transpose_f32(const float* __restrict__ in,
                                                     float* __restrict__ out,
                                                     int R, int C)
{
    __shared__ float t[64][65];
    const int r0 = blockIdx.y * 64, c0 = blockIdx.x * 64;
    const int tid = threadIdx.x;
#pragma unroll
    for (int i = 0; i < 4; ++i) {
        int c = tid + i * 256;               // 0..1023
        int r = c >> 4, q = (c & 15) * 4;
        float4 v = *(const float4*)&in[(size_t)(r0 + r) * C + c0 + q];
        t[r][q + 0] = v.x; t[r][q + 1] = v.y; t[r][q + 2] = v.z; t[r][q + 3] = v.w;
    }
    __syncthreads();
#pragma unroll
    for (int i = 0; i < 4; ++i) {
        int c = tid + i * 256;
        int orow = c >> 4, q = (c & 15) * 4;
        float4 o = make_float4(t[q + 0][orow], t[q + 1][orow], t[q + 2][orow], t[q + 3][orow]);
        *(float4*)&out[(size_t)(c0 + orow) * R + r0 + q] = o;
    }
}

// ---------------------------------------------------------------------------
// transpose bf16 [R][C] -> bf16 [C][R], batched over z with strides
// ---------------------------------------------------------------------------
__global__ __launch_bounds__(256) void transpose_b16(const u16* __restrict__ in,
                                                     u16* __restrict__ out,
                                                     int R, int C,
                                                     size_t sIn, size_t sOut)
{
    __shared__ u16 t[64][72];
    const u16* inz = in + (size_t)blockIdx.z * sIn;
    u16* outz = out + (size_t)blockIdx.z * sOut;
    const int r0 = blockIdx.y * 64, c0 = blockIdx.x * 64;
    const int tid = threadIdx.x;
#pragma unroll
    for (int i = 0; i < 2; ++i) {
        int c = tid + i * 256;               // 0..511
        int r = c >> 3, q = (c & 7) * 8;
        union { u16 u[8]; uint4 w; } v;
        v.w = *(const uint4*)&inz[(size_t)(r0 + r) * C + c0 + q];
#pragma unroll
        for (int j = 0; j < 8; ++j) t[r][q + j] = v.u[j];
    }
    __syncthreads();
#pragma unroll
    for (int i = 0; i < 2; ++i) {
        int c = tid + i * 256;
        int orow = c >> 3, os = (c & 7) * 8;
        union { u16 u[8]; uint4 w; } o;
#pragma unroll
        for (int j = 0; j < 8; ++j) o.u[j] = t[os + j][orow];
        *(uint4*)&outz[(size_t)(c0 + orow) * R + r0 + os] = o.w;
    }
}

// ---------------------------------------------------------------------------
// bf16x3 split GEMM:  C[M,N] = A[M,K] @ Bt[N,K]^T,  A/Bt fp32.
// A = Ah+Al, B = Bh+Bl (bf16 RNE splits, exact residuals);
// acc += Ah*Bh + Ah*Bl + Al*Bh  (fp32 MFMA accum)  ->  ~fp32-grade.
// 128x128 tile, BK=64, 256 thr = 4 waves (2x2), wave = 64x64 = 4x4 frags.
// LDS 16B-slot XOR swizzle (slot ^= row&7): frag ds_read_b128 2-way max.
// M mult 128, K mult 64, N arbitrary (guarded).  OUTBF16: store bf16 else f32.
// ---------------------------------------------------------------------------
template<int OUTBF16>
__global__ __launch_bounds__(256) void gemm_split(const float* __restrict__ A,
                                                  const float* __restrict__ Bt,
                                                  void* __restrict__ C,
                                                  int M, int N, int K)
{
    __shared__ __align__(16) u16 Ah[128 * 64];
    __shared__ __align__(16) u16 Al[128 * 64];
    __shared__ __align__(16) u16 Bh[128 * 64];
    __shared__ __align__(16) u16 Bl[128 * 64];

    const int tid = threadIdx.x;
    const int m0 = blockIdx.y * 128;
    const int n0 = blockIdx.x * 128;
    const int lane = tid & 63;
    const int wid = tid >> 6;
    const int wm = (wid & 1) * 64;
    const int wn = (wid >> 1) * 64;
    const int lr = lane & 15;
    const int lk = lane >> 4;

    f32x4 acc[4][4];
#pragma unroll
    for (int i = 0; i < 4; ++i)
#pragma unroll
        for (int j = 0; j < 4; ++j) acc[i][j] = {0.f, 0.f, 0.f, 0.f};

    for (int kt = 0; kt < K; kt += 64) {
        __syncthreads();
        // ---- stage A: 128 rows x 64 k (fp32 -> hi/lo bf16) ----------------
#pragma unroll
        for (int i = 0; i < 8; ++i) {
            int c = tid + i * 256;           // 0..2047
            int row = c >> 4, f4 = c & 15;
            float4 v = *(const float4*)&A[(size_t)(m0 + row) * K + kt + f4 * 4];
            union { u16 u[4]; uint2 w; } hh, ll;
            hh.u[0] = f2bf(v.x); ll.u[0] = f2bf(v.x - bf2f(hh.u[0]));
            hh.u[1] = f2bf(v.y); ll.u[1] = f2bf(v.y - bf2f(hh.u[1]));
            hh.u[2] = f2bf(v.z); ll.u[2] = f2bf(v.z - bf2f(hh.u[2]));
            hh.u[3] = f2bf(v.w); ll.u[3] = f2bf(v.w - bf2f(hh.u[3]));
            int addr = row * 64 + (((f4 >> 1) ^ (row & 7)) << 3) + (f4 & 1) * 4;
            *(uint2*)&Ah[addr] = hh.w;
            *(uint2*)&Al[addr] = ll.w;
        }
        // ---- stage B (row-guarded) ----------------------------------------
#pragma unroll
        for (int i = 0; i < 8; ++i) {
            int c = tid + i * 256;
            int row = c >> 4, f4 = c & 15;
            float4 v = make_float4(0.f, 0.f, 0.f, 0.f);
            if (n0 + row < N) v = *(const float4*)&Bt[(size_t)(n0 + row) * K + kt + f4 * 4];
            union { u16 u[4]; uint2 w; } hh, ll;
            hh.u[0] = f2bf(v.x); ll.u[0] = f2bf(v.x - bf2f(hh.u[0]));
            hh.u[1] = f2bf(v.y); ll.u[1] = f2bf(v.y - bf2f(hh.u[1]));
            hh.u[2] = f2bf(v.z); ll.u[2] = f2bf(v.z - bf2f(hh.u[2]));
            hh.u[3] = f2bf(v.w); ll.u[3] = f2bf(v.w - bf2f(hh.u[3]));
            int addr = row * 64 + (((f4 >> 1) ^ (row & 7)) << 3) + (f4 & 1) * 4;
            *(uint2*)&Bh[addr] = hh.w;
            *(uint2*)&Bl[addr] = ll.w;
        }
        __syncthreads();

#pragma unroll
        for (int ks = 0; ks < 2; ++ks) {
            bf16x8 ah[4], bh[4];
#pragma unroll
            for (int mf = 0; mf < 4; ++mf) {
                int row = wm + mf * 16 + lr;
                int sl = (ks * 4 + lk) ^ (row & 7);
                ah[mf] = *(const bf16x8*)&Ah[row * 64 + sl * 8];
            }
#pragma unroll
            for (int nf = 0; nf < 4; ++nf) {
                int row = wn + nf * 16 + lr;
                int sl = (ks * 4 + lk) ^ (row & 7);
                bh[nf] = *(const bf16x8*)&Bh[row * 64 + sl * 8];
            }
#pragma unroll
            for (int mf = 0; mf < 4; ++mf)
#pragma unroll
                for (int nf = 0; nf < 4; ++nf)
                    acc[mf][nf] = __builtin_amdgcn_mfma_f32_16x16x32_bf16(ah[mf], bh[nf], acc[mf][nf], 0, 0, 0);

            bf16x8 bl[4];
#pragma unroll
            for (int nf = 0; nf < 4; ++nf) {
                int row = wn + nf * 16 + lr;
                int sl = (ks * 4 + lk) ^ (row & 7);
                bl[nf] = *(const bf16x8*)&Bl[row * 64 + sl * 8];
            }
#pragma unroll
            for (int mf = 0; mf < 4; ++mf)
#pragma unroll
                for (int nf = 0; nf < 4; ++nf)
                    acc[mf][nf] = __builtin_amdgcn_mfma_f32_16x16x32_bf16(ah[mf], bl[nf], acc[mf][nf], 0, 0, 0);

            bf16x8 al[4];
#pragma unroll
            for (int mf = 0; mf < 4; ++mf) {
                int row = wm + mf * 16 + lr;
                int sl = (ks * 4 + lk) ^ (row & 7);
                al[mf] = *(const bf16x8*)&Al[row * 64 + sl * 8];
            }
#pragma unroll
            for (int mf = 0; mf < 4; ++mf)
#pragma unroll
                for (int nf = 0; nf < 4; ++nf)
                    acc[mf][nf] = __builtin_amdgcn_mfma_f32_16x16x32_bf16(al[mf], bh[nf], acc[mf][nf], 0, 0, 0);
        }
    }

    const int crow0 = m0 + wm + lk * 4;
    const int ccol0 = n0 + wn + lr;
#pragma unroll
    for (int mf = 0; mf < 4; ++mf)
#pragma unroll
        for (int nf = 0; nf < 4; ++nf) {
            int coln = ccol0 + nf * 16;
            if (coln < N) {
#pragma unroll
                for (int r = 0; r < 4; ++r) {
                    int rm = crow0 + mf * 16 + r;
                    float v = acc[mf][nf][r];
                    if (OUTBF16) ((u16*)C)[(size_t)rm * N + coln] = f2bf(v);
                    else         ((float*)C)[(size_t)rm * N + coln] = v;
                }
            }
        }
}

// ---------------------------------------------------------------------------
// pope: read fp32 [B*S, hcols*64], apply softplus+rotation, write bf16.
// pair (j, j+32) within each 64-wide head chunk shares angle j.
// ---------------------------------------------------------------------------
__device__ __forceinline__ float softplusf(float v)
{
    if (v > 20.f) return v;
    return log1pf(__expf(v));
}

__global__ __launch_bounds__(256) void pope_split(const float* __restrict__ in,
                                                  u16* __restrict__ outb,
                                                  const float* __restrict__ delta,
                                                  int hcols)
{
    const int idx = blockIdx.x * 256 + threadIdx.x;
    const int total = BATCH * SEQ * hcols * 32;
    if (idx >= total) return;
    const int j = idx & 31;
    const int h = (idx >> 5) % hcols;
    const int rowid = idx / (32 * hcols);
    const int s = rowid % SEQ;

    const float theta = __expf(-(2.0f * (float)j) * (9.210340371976184f / 64.0f));
    const float ang = (float)s * theta + delta[j];
    float sn, cs;
    sincosf(ang, &sn, &cs);

    const float* row = in + (size_t)rowid * (hcols * 64) + h * 64;
    u16* orow = outb + (size_t)rowid * (hcols * 64) + h * 64;
    const float mu1 = softplusf(row[j]);
    const float mu2 = softplusf(row[j + 32]);
    orow[j]      = f2bf(mu1 * cs - mu2 * sn);
    orow[j + 32] = f2bf(mu1 * sn + mu2 * cs);
}

// ---------------------------------------------------------------------------
// MFMA flash attention.  grid (SEQ/64, BATCH*NHEAD), 256 thr = 4 waves.
// Wave w owns q-rows w*16..w*16+15 of the 64-row q-tile.
// S = Q*K^T via 16x16x32 (A=Q regs, B=K from LDS), online softmax fp32,
// P -> bf16 -> per-wave LDS, out += P*V (B=V^T from LDS).
// All LDS fragment rows use 16B-slot XOR swizzle (slot ^= row&7).
// Output ao is fp32 (feeds the split final projection).
// ---------------------------------------------------------------------------
__global__ __launch_bounds__(256) void attn_mfma(const u16* __restrict__ qc,
                                                 const u16* __restrict__ qr,
                                                 const u16* __restrict__ kc,
                                                 const u16* __restrict__ kr,
                                                 const u16* __restrict__ vt,
                                                 float* __restrict__ ao)
{
    __shared__ __align__(16) u16 Ks[64 * 192];     // [key][24 slots]
    __shared__ __align__(16) u16 Vs[128 * 64];     // [d][8 slots]
    __shared__ __align__(16) u16 Ps[4][16 * 64];   // per-wave [q][8 slots]

    const int qi = gridDim.x - 1 - blockIdx.x;     // big blocks first
    const int q0 = qi * 64;
    const int bh = blockIdx.y;
    const int b = bh >> 4, h = bh & 15;
    const int tid = threadIdx.x, lane = tid & 63, wid = tid >> 6;
    const int lr = lane & 15, lk = lane >> 4;
    const float scale = 0.07216878364870323f;      // 1/sqrt(192)

    // Q fragments (A-operand rows = lane&15), hoisted
    bf16x8 qf[6];
    {
        const int sq = q0 + wid * 16 + lr;
        const size_t qb = ((size_t)(b * SEQ + sq)) * (NHEAD * DHEAD) + h * DHEAD;
        const size_t rb = ((size_t)(b * SEQ + sq)) * (NHEAD * DROPE) + h * DROPE;
#pragma unroll
        for (int ks = 0; ks < 4; ++ks) qf[ks] = *(const bf16x8*)&qc[qb + ks * 32 + lk * 8];
#pragma unroll
        for (int ks = 4; ks < 6; ++ks) qf[ks] = *(const bf16x8*)&qr[rb + (ks - 4) * 32 + lk * 8];
    }

    f32x4 oacc[8];
#pragma unroll
    for (int nf = 0; nf < 8; ++nf) oacc[nf] = {0.f, 0.f, 0.f, 0.f};
    float mrow[4] = {-1e30f, -1e30f, -1e30f, -1e30f};
    float lrow[4] = {0.f, 0.f, 0.f, 0.f};

    for (int k0 = 0; k0 <= q0; k0 += 64) {
        __syncthreads();
        // ---- stage K tile: 64 rows x 24 slots -----------------------------
#pragma unroll
        for (int i = 0; i < 6; ++i) {
            int c = tid + i * 256;                 // 0..1535
            int row = c / 24, sl = c - row * 24;
            int key = k0 + row;
            uint4 v;
            if (sl < 16) v = *(const uint4*)&kc[((size_t)(b * SEQ + key)) * (NHEAD * DHEAD) + h * DHEAD + sl * 8];
            else         v = *(const uint4*)&kr[((size_t)(b * SEQ + key)) * DROPE + (sl - 16) * 8];
            int sls = (sl & 24) | ((sl & 7) ^ (row & 7));
            *(uint4*)&Ks[(row * 24 + sls) * 8] = v;
        }
        // ---- stage V^T tile: 128 d-rows x 8 slots -------------------------
#pragma unroll
        for (int i = 0; i < 4; ++i) {
            int c = tid + i * 256;                 // 0..1023
            int d = c >> 3, sl = c & 7;
            uint4 v = *(const uint4*)&vt[((size_t)(bh * DHEAD + d)) * SEQ + k0 + sl * 8];
            *(uint4*)&Vs[(d * 8 + (sl ^ (d & 7))) * 8] = v;
        }
        __syncthreads();

        // ---- S = Q*K^T ----------------------------------------------------
        f32x4 sf[4];
#pragma unroll
        for (int nf = 0; nf < 4; ++nf) sf[nf] = {0.f, 0.f, 0.f, 0.f};
#pragma unroll
        for (int ks = 0; ks < 6; ++ks) {
#pragma unroll
            for (int nf = 0; nf < 4; ++nf) {
                int row = nf * 16 + lr;
                int slb = ks * 4 + lk;             // 0..23
                int sls = (slb & 24) | ((slb & 7) ^ (row & 7));
                bf16x8 kf = *(const bf16x8*)&Ks[(row * 24 + sls) * 8];
                sf[nf] = __builtin_amdgcn_mfma_f32_16x16x32_bf16(qf[ks], kf, sf[nf], 0, 0, 0);
            }
        }
        // scale + causal mask (diagonal tile only)
#pragma unroll
        for (int nf = 0; nf < 4; ++nf)
#pragma unroll
            for (int r = 0; r < 4; ++r) sf[nf][r] *= scale;
        if (k0 == q0) {
#pragma unroll
            for (int nf = 0; nf < 4; ++nf) {
                int key = k0 + nf * 16 + lr;
#pragma unroll
                for (int r = 0; r < 4; ++r) {
                    int q = q0 + wid * 16 + lk * 4 + r;
                    if (key > q) sf[nf][r] = -3.0e38f;
                }
            }
        }

        // ---- online softmax (per row r; stats shared across 16-lane group)
#pragma unroll
        for (int r = 0; r < 4; ++r) {
            float mx = fmaxf(fmaxf(sf[0][r], sf[1][r]), fmaxf(sf[2][r], sf[3][r]));
            mx = fmaxf(mx, __shfl_xor(mx, 1));
            mx = fmaxf(mx, __shfl_xor(mx, 2));
            mx = fmaxf(mx, __shfl_xor(mx, 4));
            mx = fmaxf(mx, __shfl_xor(mx, 8));
            const float mnew = fmaxf(mrow[r], mx);
            const float alpha = __expf(mrow[r] - mnew);
            float ps = 0.f;
#pragma unroll
            for (int nf = 0; nf < 4; ++nf) {
                float p = __expf(sf[nf][r] - mnew);
                sf[nf][r] = p;
                ps += p;
            }
            ps += __shfl_xor(ps, 1);
            ps += __shfl_xor(ps, 2);
            ps += __shfl_xor(ps, 4);
            ps += __shfl_xor(ps, 8);
            lrow[r] = lrow[r] * alpha + ps;
            mrow[r] = mnew;
#pragma unroll
            for (int nf = 0; nf < 8; ++nf) oacc[nf][r] *= alpha;
        }

        // ---- P -> bf16 -> per-wave LDS (swizzled) -------------------------
        u16* pw = &Ps[wid][0];
#pragma unroll
        for (int nf = 0; nf < 4; ++nf)
#pragma unroll
            for (int r = 0; r < 4; ++r) {
                int prow = lk * 4 + r;
                int col = nf * 16 + lr;
                int sl = (col >> 3) ^ (prow & 7);
                pw[(prow * 8 + sl) * 8 + (col & 7)] = f2bf(sf[nf][r]);
            }

        // ---- out += P*V ---------------------------------------------------
#pragma unroll
        for (int kp = 0; kp < 2; ++kp) {
            int sla = (kp * 4 + lk) ^ (lr & 7);
            bf16x8 pa = *(const bf16x8*)&pw[(lr * 8 + sla) * 8];
#pragma unroll
            for (int nf = 0; nf < 8; ++nf) {
                int vrow = nf * 16 + lr;
                int slv = (kp * 4 + lk) ^ (vrow & 7);
                bf16x8 vf = *(const bf16x8*)&Vs[(vrow * 8 + slv) * 8];
                oacc[nf] = __builtin_amdgcn_mfma_f32_16x16x32_bf16(pa, vf, oacc[nf], 0, 0, 0);
            }
        }
    }

    // ---- epilogue (fp32) --------------------------------------------------
#pragma unroll
    for (int nf = 0; nf < 8; ++nf)
#pragma unroll
        for (int r = 0; r < 4; ++r) {
            int q = q0 + wid * 16 + lk * 4 + r;
            int d = nf * 16 + lr;
            ao[((size_t)(b * SEQ + q)) * (NHEAD * DHEAD) + h * DHEAD + d] = oacc[nf][r] / lrow[r];
        }
}

// ---------------------------------------------------------------------------
// Workspace map (float units, total 36,962,304 f = 147.85 MB; round-1 proved
// >= 152 MB available).  Reuse: ao overlays ckv+cq+vvb (dead by attention);
// vt overlays wdkvT/wdqT/wkrT (dead after x-projections); qrb/krb16 overlay
// wuqT/wqrT (dead after q-projections).
// ---------------------------------------------------------------------------
extern "C" void kernel_launch(void* const* d_in, const int* in_sizes, int n_in,
                              void* d_out, int out_size, void* d_ws, size_t ws_size,
                              hipStream_t stream)
{
    const float* x     = (const float*)d_in[0];
    const float* w_dkv = (const float*)d_in[1];
    const float* w_uk  = (const float*)d_in[2];
    const float* w_uv  = (const float*)d_in[3];
    const float* w_dq  = (const float*)d_in[4];
    const float* w_uq  = (const float*)d_in[5];
    const float* w_qr  = (const float*)d_in[6];
    const float* w_kr  = (const float*)d_in[7];
    const float* w_out = (const float*)d_in[8];
    const float* delta = (const float*)d_in[9];
    float* out = (float*)d_out;
    float* ws = (float*)d_ws;

    const int M = BATCH * SEQ;   // 4096

    float* ckv   = ws;                          // f32 [4096][512]
    float* cq    = ws + 2097152;                // f32 [4096][1024]
    u16*   vvb   = (u16*)(ws + 6291456);        // bf16 [4096][2048]
    float* ao    = ws;                          // f32 [4096][2048] (later)
    u16*   kc    = (u16*)(ws + 10485760);       // bf16 [4096][2048]
    u16*   qc    = (u16*)(ws + 14680064);       // bf16 [4096][2048]
    float* qr32  = ws + 18874368;               // f32 [4096][1024]
    float* kr32  = ws + 23068672;               // f32 [4096][64]
    u16*   vt    = (u16*)(ws + 23330816);       // bf16 [2][2048][2048]
    float* wdkvT = ws + 23330816;               // (pre-vt scratch)
    float* wdqT  = ws + 24379392;
    float* wkrT  = ws + 26476544;
    float* wukT  = ws + 27525120;
    float* wuvT  = ws + 28573696;
    float* wuqT  = ws + 29622272;
    u16*   qrb   = (u16*)(ws + 29622272);       // bf16 [4096][1024] (post-uq)
    float* wqrT  = ws + 31719424;
    u16*   krb16 = (u16*)(ws + 31719424);       // bf16 [4096][64]   (post-qr)
    float* woutT = ws + 32768000;

    dim3 blk(256);

    // ---- weight transposes (fp32) ----------------------------------------
    transpose_f32<<<dim3(8, 32), blk, 0, stream>>>(w_dkv, wdkvT, DMODEL, DCKV);
    transpose_f32<<<dim3(16, 32), blk, 0, stream>>>(w_dq, wdqT, DMODEL, DCQ);
    transpose_f32<<<dim3(1, 32), blk, 0, stream>>>(w_kr, wkrT, DMODEL, DROPE);
    transpose_f32<<<dim3(32, 8), blk, 0, stream>>>(w_uk, wukT, DCKV, 2048);
    transpose_f32<<<dim3(32, 8), blk, 0, stream>>>(w_uv, wuvT, DCKV, 2048);
    transpose_f32<<<dim3(32, 16), blk, 0, stream>>>(w_uq, wuqT, DCQ, 2048);
    transpose_f32<<<dim3(16, 16), blk, 0, stream>>>(w_qr, wqrT, DCQ, 1024);
    transpose_f32<<<dim3(32, 32), blk, 0, stream>>>(w_out, woutT, 2048, DMODEL);

    // ---- projections (bf16x3 split GEMMs) --------------------------------
    gemm_split<0><<<dim3(4, 32), blk, 0, stream>>>(x, wdkvT, ckv, M, DCKV, DMODEL);
    gemm_split<0><<<dim3(8, 32), blk, 0, stream>>>(x, wdqT, cq, M, DCQ, DMODEL);
    gemm_split<0><<<dim3(1, 32), blk, 0, stream>>>(x, wkrT, kr32, M, DROPE, DMODEL);
    gemm_split<1><<<dim3(16, 32), blk, 0, stream>>>(ckv, wukT, kc, M, 2048, DCKV);
    gemm_split<1><<<dim3(16, 32), blk, 0, stream>>>(ckv, wuvT, vvb, M, 2048, DCKV);
    gemm_split<1><<<dim3(16, 32), blk, 0, stream>>>(cq, wuqT, qc, M, 2048, DCQ);
    gemm_split<0><<<dim3(8, 32), blk, 0, stream>>>(cq, wqrT, qr32, M, NHEAD * DROPE, DCQ);

    // ---- rope (fp32 in, bf16 out) ----------------------------------------
    pope_split<<<dim3(8192), blk, 0, stream>>>(qr32, qrb, delta, NHEAD);
    pope_split<<<dim3(512), blk, 0, stream>>>(kr32, krb16, delta, 1);

    // ---- V -> V^T per batch ----------------------------------------------
    transpose_b16<<<dim3(32, 32, BATCH), blk, 0, stream>>>(vvb, vt, SEQ, 2048,
                                                           (size_t)SEQ * 2048, (size_t)SEQ * 2048);

    // ---- attention (fp32 out) --------------------------------------------
    attn_mfma<<<dim3(SEQ / 64, BATCH * NHEAD), blk, 0, stream>>>(qc, qrb, kc, krb16, vt, ao);

    // ---- output projection (split, fp32 out) -----------------------------
    gemm_split<0><<<dim3(16, 32), blk, 0, stream>>>(ao, woutT, out, M, DMODEL, 2048);
}

// Round 6
// 824.394 us; speedup vs baseline: 6.4681x; 1.5608x over previous
//
#include <hip/hip_runtime.h>
#include <math.h>

#define BATCH  2
#define SEQ    2048
#define NHEAD  16
#define DMODEL 2048
#define DCKV   512
#define DCQ    1024
#define DHEAD  128
#define DROPE  64

typedef unsigned short u16;
typedef __attribute__((ext_vector_type(8))) short bf16x8;
typedef __attribute__((ext_vector_type(4))) float f32x4;

__device__ __forceinline__ u16 f2bf(float f) {           // RNE
    union { float f; unsigned u; } v; v.f = f;
    unsigned r = v.u + 0x7FFFu + ((v.u >> 16) & 1u);
    return (u16)(r >> 16);
}
__device__ __forceinline__ float bf2f(u16 h) {
    union { unsigned u; float f; } v; v.u = ((unsigned)h) << 16;
    return v.f;
}

// async global->LDS, 16B per lane; lds dest must be wave-uniform base (+lane*16)
__device__ __forceinline__ void gload_lds16(const u16* g, u16* l) {
    typedef const __attribute__((address_space(1))) u16* gp_t;
    typedef __attribute__((address_space(3))) u16* lp_t;
    __builtin_amdgcn_global_load_lds((gp_t)g, (lp_t)l, 16, 0, 0);
}

// ---------------------------------------------------------------------------
// flat f32 -> bf16 convert (n multiple of 4)
// ---------------------------------------------------------------------------
__global__ __launch_bounds__(256) void convert_bf16(const float* __restrict__ in,
                                                    u16* __restrict__ out, int n)
{
    int i = (blockIdx.x * 256 + threadIdx.x) * 4;
    if (i >= n) return;
    float4 v = *(const float4*)&in[i];
    union { u16 u[4]; uint2 w; } o;
    o.u[0] = f2bf(v.x); o.u[1] = f2bf(v.y); o.u[2] = f2bf(v.z); o.u[3] = f2bf(v.w);
    *(uint2*)&out[i] = o.w;
}

// ---------------------------------------------------------------------------
// transpose+convert: in f32 [R][C] -> out bf16 [C][R].  R,C multiples of 64.
// ---------------------------------------------------------------------------
__global__ __launch_bounds__(256) void transpose_f32_bf16(const float* __restrict__ in,
                                                          u16* __restrict__ out,
                                                          int R, int C)
{
    __shared__ u16 t[64][70];
    const int r0 = blockIdx.y * 64, c0 = blockIdx.x * 64;
    const int tid = threadIdx.x;
#pragma unroll
    for (int i = 0; i < 4; ++i) {
        int c = tid + i * 256;           // 0..1023
        int r = c >> 4, q = (c & 15) * 4;
        float4 v = *(const float4*)&in[(size_t)(r0 + r) * C + c0 + q];
        t[r][q + 0] = f2bf(v.x); t[r][q + 1] = f2bf(v.y);
        t[r][q + 2] = f2bf(v.z); t[r][q + 3] = f2bf(v.w);
    }
    __syncthreads();
#pragma unroll
    for (int i = 0; i < 2; ++i) {
        int c = tid + i * 256;           // 0..511
        int orow = c >> 3, os = (c & 7) * 8;
        union { u16 u[8]; uint4 w; } o;
#pragma unroll
        for (int j = 0; j < 8; ++j) o.u[j] = t[os + j][orow];
        *(uint4*)&out[(size_t)(c0 + orow) * R + r0 + os] = o.w;
    }
}

// ---------------------------------------------------------------------------
// transpose bf16 [R][C] -> bf16 [C][R], batched over z with strides
// ---------------------------------------------------------------------------
__global__ __launch_bounds__(256) void transpose_b16(const u16* __restrict__ in,
                                                     u16* __restrict__ out,
                                                     int R, int C,
                                                     size_t sIn, size_t sOut)
{
    __shared__ u16 t[64][72];
    const u16* inz = in + (size_t)blockIdx.z * sIn;
    u16* outz = out + (size_t)blockIdx.z * sOut;
    const int r0 = blockIdx.y * 64, c0 = blockIdx.x * 64;
    const int tid = threadIdx.x;
#pragma unroll
    for (int i = 0; i < 2; ++i) {
        int c = tid + i * 256;           // 0..511
        int r = c >> 3, q = (c & 7) * 8;
        union { u16 u[8]; uint4 w; } v;
        v.w = *(const uint4*)&inz[(size_t)(r0 + r) * C + c0 + q];
#pragma unroll
        for (int j = 0; j < 8; ++j) t[r][q + j] = v.u[j];
    }
    __syncthreads();
#pragma unroll
    for (int i = 0; i < 2; ++i) {
        int c = tid + i * 256;
        int orow = c >> 3, os = (c & 7) * 8;
        union { u16 u[8]; uint4 w; } o;
#pragma unroll
        for (int j = 0; j < 8; ++j) o.u[j] = t[os + j][orow];
        *(uint4*)&outz[(size_t)(c0 + orow) * R + r0 + os] = o.w;
    }
}

// ---------------------------------------------------------------------------
// bf16 MFMA GEMM: C[M,N] = A[M,K] * Bt[N,K]^T, fp32 accum.
// 128x128 tile, BK=64, 256 thr = 4 waves (2x2), wave = 64x64 = 4x4 frags.
// Staging: global_load_lds x16 with pre-swizzled per-lane SOURCE and linear
// LDS dest; frag reads apply the same involutive XOR (16B slot ^= row&7).
// M mult 128, K mult 64; N mult 128 OR (N<128 with Bt rows padded to 128).
// OUTBF16: store bf16 else f32.
// ---------------------------------------------------------------------------
template<int OUTBF16>
__global__ __launch_bounds__(256) void gemm_bf16(const u16* __restrict__ A,
                                                 const u16* __restrict__ Bt,
                                                 void* __restrict__ C,
                                                 int M, int N, int K)
{
    __shared__ __align__(16) u16 As[128 * 64];
    __shared__ __align__(16) u16 Bs[128 * 64];

    const int tid = threadIdx.x;
    const int m0 = blockIdx.y * 128;
    const int n0 = blockIdx.x * 128;
    const int lane = tid & 63;
    const int wid = tid >> 6;
    const int wm = (wid & 1) * 64;
    const int wn = (wid >> 1) * 64;
    const int lr = lane & 15;
    const int lk = lane >> 4;

    f32x4 acc[4][4];
#pragma unroll
    for (int i = 0; i < 4; ++i)
#pragma unroll
        for (int j = 0; j < 4; ++j) acc[i][j] = {0.f, 0.f, 0.f, 0.f};

    for (int kt = 0; kt < K; kt += 64) {
        __syncthreads();
        // ---- stage A,B: linear LDS dest, inverse-swizzled global source ---
#pragma unroll
        for (int i = 0; i < 4; ++i) {
            int d0 = (i * 4 + wid) * 64;
            int d = d0 + lane;
            int row = d >> 3, sl = d & 7;
            gload_lds16(&A[(size_t)(m0 + row) * K + kt + ((sl ^ (row & 7)) << 3)], &As[d0 * 8]);
        }
#pragma unroll
        for (int i = 0; i < 4; ++i) {
            int d0 = (i * 4 + wid) * 64;
            int d = d0 + lane;
            int row = d >> 3, sl = d & 7;
            gload_lds16(&Bt[(size_t)(n0 + row) * K + kt + ((sl ^ (row & 7)) << 3)], &Bs[d0 * 8]);
        }
        __syncthreads();   // compiler drains vmcnt before s_barrier

#pragma unroll
        for (int ks = 0; ks < 2; ++ks) {
            bf16x8 af[4], bfr[4];
#pragma unroll
            for (int mf = 0; mf < 4; ++mf) {
                int row = wm + mf * 16 + lr;
                int sl = (ks * 4 + lk) ^ (row & 7);
                af[mf] = *(const bf16x8*)&As[row * 64 + sl * 8];
            }
#pragma unroll
            for (int nf = 0; nf < 4; ++nf) {
                int row = wn + nf * 16 + lr;
                int sl = (ks * 4 + lk) ^ (row & 7);
                bfr[nf] = *(const bf16x8*)&Bs[row * 64 + sl * 8];
            }
#pragma unroll
            for (int mf = 0; mf < 4; ++mf)
#pragma unroll
                for (int nf = 0; nf < 4; ++nf)
                    acc[mf][nf] = __builtin_amdgcn_mfma_f32_16x16x32_bf16(
                        af[mf], bfr[nf], acc[mf][nf], 0, 0, 0);
        }
    }

    const int crow0 = m0 + wm + lk * 4;
    const int ccol0 = n0 + wn + lr;
#pragma unroll
    for (int mf = 0; mf < 4; ++mf)
#pragma unroll
        for (int nf = 0; nf < 4; ++nf) {
            int coln = ccol0 + nf * 16;
            if (coln < N) {
#pragma unroll
                for (int r = 0; r < 4; ++r) {
                    int rm = crow0 + mf * 16 + r;
                    float v = acc[mf][nf][r];
                    if (OUTBF16) ((u16*)C)[(size_t)rm * N + coln] = f2bf(v);
                    else         ((float*)C)[(size_t)rm * N + coln] = v;
                }
            }
        }
}

// ---------------------------------------------------------------------------
// pope: read fp32 [B*S, hcols*64], softplus+rotate, write bf16.
// ---------------------------------------------------------------------------
__device__ __forceinline__ float softplusf(float v)
{
    if (v > 20.f) return v;
    return log1pf(__expf(v));
}

__global__ __launch_bounds__(256) void pope_split(const float* __restrict__ in,
                                                  u16* __restrict__ outb,
                                                  const float* __restrict__ delta,
                                                  int hcols)
{
    const int idx = blockIdx.x * 256 + threadIdx.x;
    const int total = BATCH * SEQ * hcols * 32;
    if (idx >= total) return;
    const int j = idx & 31;
    const int h = (idx >> 5) % hcols;
    const int rowid = idx / (32 * hcols);
    const int s = rowid % SEQ;

    const float theta = __expf(-(2.0f * (float)j) * (9.210340371976184f / 64.0f));
    const float ang = (float)s * theta + delta[j];
    float sn, cs;
    sincosf(ang, &sn, &cs);

    const float* row = in + (size_t)rowid * (hcols * 64) + h * 64;
    u16* orow = outb + (size_t)rowid * (hcols * 64) + h * 64;
    const float mu1 = softplusf(row[j]);
    const float mu2 = softplusf(row[j + 32]);
    orow[j]      = f2bf(mu1 * cs - mu2 * sn);
    orow[j + 32] = f2bf(mu1 * sn + mu2 * cs);
}

// ---------------------------------------------------------------------------
// MFMA flash attention v2.  grid (SEQ/128, BATCH*NHEAD), 256 thr = 4 waves.
// 128-row q-tile; wave w owns rows [w*32, w*32+32) as 2 row-frags of 16.
// Each K/V B-frag read feeds 2 MFMAs (row-frag reuse) -> half the LDS reads
// per FLOP vs the 16-row layout.  P goes to the Ks region (free during PV).
// LDS: Ks 24KB + Vs 16KB = 40KB.  3 barriers/tile.  ao output bf16.
// ---------------------------------------------------------------------------
__global__ __launch_bounds__(256) void attn_mfma(const u16* __restrict__ qc,
                                                 const u16* __restrict__ qr,
                                                 const u16* __restrict__ kc,
                                                 const u16* __restrict__ kr,
                                                 const u16* __restrict__ vt,
                                                 u16* __restrict__ ao)
{
    __shared__ __align__(16) u16 Ks[64 * 192];     // [key][24 slots]; P alias
    __shared__ __align__(16) u16 Vs[128 * 64];     // [d][8 slots]

    const int qi = gridDim.x - 1 - blockIdx.x;     // big blocks first
    const int q0 = qi * 128;
    const int bh = blockIdx.y;
    const int b = bh >> 4, h = bh & 15;
    const int tid = threadIdx.x, lane = tid & 63, wid = tid >> 6;
    const int lr = lane & 15, lk = lane >> 4;
    const float scale = 0.07216878364870323f;      // 1/sqrt(192)

    // Q fragments: 2 row-frags x 6 k-slots
    bf16x8 qf[2][6];
#pragma unroll
    for (int rf = 0; rf < 2; ++rf) {
        const int sq = q0 + wid * 32 + rf * 16 + lr;
        const size_t qb = ((size_t)(b * SEQ + sq)) * (NHEAD * DHEAD) + h * DHEAD;
        const size_t rb = ((size_t)(b * SEQ + sq)) * (NHEAD * DROPE) + h * DROPE;
#pragma unroll
        for (int ks = 0; ks < 4; ++ks) qf[rf][ks] = *(const bf16x8*)&qc[qb + ks * 32 + lk * 8];
#pragma unroll
        for (int ks = 4; ks < 6; ++ks) qf[rf][ks] = *(const bf16x8*)&qr[rb + (ks - 4) * 32 + lk * 8];
    }

    f32x4 oacc[2][8];
#pragma unroll
    for (int rf = 0; rf < 2; ++rf)
#pragma unroll
        for (int nf = 0; nf < 8; ++nf) oacc[rf][nf] = {0.f, 0.f, 0.f, 0.f};
    float mrow[2][4], lrow[2][4];
#pragma unroll
    for (int rf = 0; rf < 2; ++rf)
#pragma unroll
        for (int r = 0; r < 4; ++r) { mrow[rf][r] = -1e30f; lrow[rf][r] = 0.f; }

    const int ktiles = q0 / 64 + 2;
    for (int t = 0; t < ktiles; ++t) {
        const int k0 = t * 64;
        __syncthreads();                           // prior PV (Ks-alias & Vs reads) done
        // ---- stage K tile: 64 rows x 24 slots -----------------------------
#pragma unroll
        for (int i = 0; i < 6; ++i) {
            int c = tid + i * 256;                 // 0..1535
            int row = c / 24, sl = c - row * 24;
            int key = k0 + row;
            uint4 v;
            if (sl < 16) v = *(const uint4*)&kc[((size_t)(b * SEQ + key)) * (NHEAD * DHEAD) + h * DHEAD + sl * 8];
            else         v = *(const uint4*)&kr[((size_t)(b * SEQ + key)) * DROPE + (sl - 16) * 8];
            int sls = (sl & 24) | ((sl & 7) ^ (row & 7));
            *(uint4*)&Ks[(row * 24 + sls) * 8] = v;
        }
        // ---- stage V^T tile: 128 d-rows x 8 slots -------------------------
#pragma unroll
        for (int i = 0; i < 4; ++i) {
            int c = tid + i * 256;                 // 0..1023
            int d = c >> 3, sl = c & 7;
            uint4 v = *(const uint4*)&vt[((size_t)(bh * DHEAD + d)) * SEQ + k0 + sl * 8];
            *(uint4*)&Vs[(d * 8 + (sl ^ (d & 7))) * 8] = v;
        }
        __syncthreads();

        const bool active = (k0 <= q0 + wid * 32 + 31);
        f32x4 sf[2][4];
        if (active) {
            // ---- S = Q*K^T ------------------------------------------------
#pragma unroll
            for (int rf = 0; rf < 2; ++rf)
#pragma unroll
                for (int nf = 0; nf < 4; ++nf) sf[rf][nf] = {0.f, 0.f, 0.f, 0.f};
            __builtin_amdgcn_s_setprio(1);
#pragma unroll
            for (int ks = 0; ks < 6; ++ks) {
                bf16x8 kf[4];
#pragma unroll
                for (int nf = 0; nf < 4; ++nf) {
                    int row = nf * 16 + lr;
                    int slb = ks * 4 + lk;
                    int sls = (slb & 24) | ((slb & 7) ^ (row & 7));
                    kf[nf] = *(const bf16x8*)&Ks[(row * 24 + sls) * 8];
                }
#pragma unroll
                for (int rf = 0; rf < 2; ++rf)
#pragma unroll
                    for (int nf = 0; nf < 4; ++nf)
                        sf[rf][nf] = __builtin_amdgcn_mfma_f32_16x16x32_bf16(
                            qf[rf][ks], kf[nf], sf[rf][nf], 0, 0, 0);
            }
            __builtin_amdgcn_s_setprio(0);

            // ---- scale + causal mask + online softmax ---------------------
#pragma unroll
            for (int rf = 0; rf < 2; ++rf) {
                const int qbase = q0 + wid * 32 + rf * 16;
#pragma unroll
                for (int nf = 0; nf < 4; ++nf)
#pragma unroll
                    for (int r = 0; r < 4; ++r) sf[rf][nf][r] *= scale;
                if (k0 + 63 > qbase) {
#pragma unroll
                    for (int nf = 0; nf < 4; ++nf) {
                        int key = k0 + nf * 16 + lr;
#pragma unroll
                        for (int r = 0; r < 4; ++r)
                            if (key > qbase + lk * 4 + r) sf[rf][nf][r] = -3.0e38f;
                    }
                }
#pragma unroll
                for (int r = 0; r < 4; ++r) {
                    float mx = fmaxf(fmaxf(sf[rf][0][r], sf[rf][1][r]),
                                     fmaxf(sf[rf][2][r], sf[rf][3][r]));
                    mx = fmaxf(mx, __shfl_xor(mx, 1));
                    mx = fmaxf(mx, __shfl_xor(mx, 2));
                    mx = fmaxf(mx, __shfl_xor(mx, 4));
                    mx = fmaxf(mx, __shfl_xor(mx, 8));
                    const float mnew = fmaxf(mrow[rf][r], mx);
                    const float alpha = __expf(mrow[rf][r] - mnew);
                    float ps = 0.f;
#pragma unroll
                    for (int nf = 0; nf < 4; ++nf) {
                        float p = __expf(sf[rf][nf][r] - mnew);
                        sf[rf][nf][r] = p;
                        ps += p;
                    }
                    ps += __shfl_xor(ps, 1);
                    ps += __shfl_xor(ps, 2);
                    ps += __shfl_xor(ps, 4);
                    ps += __shfl_xor(ps, 8);
                    lrow[rf][r] = lrow[rf][r] * alpha + ps;
                    mrow[rf][r] = mnew;
#pragma unroll
                    for (int nf = 0; nf < 8; ++nf) oacc[rf][nf][r] *= alpha;
                }
            }
        }
        __syncthreads();                           // all QK reads of Ks done

        if (active) {
            // ---- P -> bf16 -> Ks-alias region (per-wave 4KB, swizzled) ----
            u16* pw = &Ks[wid * 2048];
#pragma unroll
            for (int rf = 0; rf < 2; ++rf)
#pragma unroll
                for (int nf = 0; nf < 4; ++nf)
#pragma unroll
                    for (int r = 0; r < 4; ++r) {
                        int prow = rf * 16 + lk * 4 + r;
                        int col = nf * 16 + lr;
                        int sl = (col >> 3) ^ (prow & 7);
                        pw[(prow * 8 + sl) * 8 + (col & 7)] = f2bf(sf[rf][nf][r]);
                    }
            // ---- out += P*V ----------------------------------------------
            __builtin_amdgcn_s_setprio(1);
#pragma unroll
            for (int kp = 0; kp < 2; ++kp) {
                bf16x8 pa[2];
#pragma unroll
                for (int rf = 0; rf < 2; ++rf) {
                    int prow = rf * 16 + lr;
                    int sla = (kp * 4 + lk) ^ (prow & 7);
                    pa[rf] = *(const bf16x8*)&pw[(prow * 8 + sla) * 8];
                }
#pragma unroll
                for (int nf = 0; nf < 8; ++nf) {
                    int vrow = nf * 16 + lr;
                    int slv = (kp * 4 + lk) ^ (vrow & 7);
                    bf16x8 vf = *(const bf16x8*)&Vs[(vrow * 8 + slv) * 8];
#pragma unroll
                    for (int rf = 0; rf < 2; ++rf)
                        oacc[rf][nf] = __builtin_amdgcn_mfma_f32_16x16x32_bf16(
                            pa[rf], vf, oacc[rf][nf], 0, 0, 0);
                }
            }
            __builtin_amdgcn_s_setprio(0);
        }
    }

    // ---- epilogue (bf16) --------------------------------------------------
#pragma unroll
    for (int rf = 0; rf < 2; ++rf)
#pragma unroll
        for (int nf = 0; nf < 8; ++nf)
#pragma unroll
            for (int r = 0; r < 4; ++r) {
                int q = q0 + wid * 32 + rf * 16 + lk * 4 + r;
                int d = nf * 16 + lr;
                ao[((size_t)(b * SEQ + q)) * (NHEAD * DHEAD) + h * DHEAD + d] =
                    f2bf(oacc[rf][nf][r] / lrow[rf][r]);
            }
}

// ---------------------------------------------------------------------------
// Workspace map (u16 units; total 74,448,896 = 148.9 MB; round-1 proved
// >= 152 MB available).  ao aliases vv (dead after the V^T transpose).
// wkrT padded to 128 rows (rows 64..127 read as 0xAA garbage — finite bf16 —
// and guarded at C-write).  FIX vs r4: qrb moved past kr32's full u16 extent.
// ---------------------------------------------------------------------------
extern "C" void kernel_launch(void* const* d_in, const int* in_sizes, int n_in,
                              void* d_out, int out_size, void* d_ws, size_t ws_size,
                              hipStream_t stream)
{
    const float* x     = (const float*)d_in[0];
    const float* w_dkv = (const float*)d_in[1];
    const float* w_uk  = (const float*)d_in[2];
    const float* w_uv  = (const float*)d_in[3];
    const float* w_dq  = (const float*)d_in[4];
    const float* w_uq  = (const float*)d_in[5];
    const float* w_qr  = (const float*)d_in[6];
    const float* w_kr  = (const float*)d_in[7];
    const float* w_out = (const float*)d_in[8];
    const float* delta = (const float*)d_in[9];
    float* out = (float*)d_out;
    u16* ws = (u16*)d_ws;

    const int M = BATCH * SEQ;   // 4096

    u16* xb    = ws;                         // [4096][2048]            [0,        8388608)
    u16* ckv   = ws + 8388608;               // [4096][512]             [8388608, 10485760)
    u16* cq    = ws + 10485760;              // [4096][1024]            [10485760,14680064)
    u16* kc    = ws + 14680064;              // [4096][2048]            [14680064,23068672)
    u16* qc    = ws + 23068672;              // [4096][2048]            [23068672,31457280)
    u16* vv    = ws + 31457280;              // [4096][2048]            [31457280,39845888)
    u16* ao    = ws + 31457280;              // aliases vv (dead after V^T)
    u16* vt    = ws + 39845888;              // [2][2048][2048]         [39845888,48234496)
    float* qr32 = (float*)(ws + 48234496);   // f32 [4096][1024] = 8388608 u16  [48234496,56623104)
    float* kr32 = (float*)(ws + 56623104);   // f32 [4096][64]   =  524288 u16  [56623104,57147392)
    u16* qrb   = ws + 57147392;              // [4096][1024]            [57147392,61341696)
    u16* krb   = ws + 61341696;              // [4096][64]              [61341696,61603840)
    u16* wdkvT = ws + 61603840;              // [512][2048]             [61603840,62652416)
    u16* wdqT  = ws + 62652416;              // [1024][2048]            [62652416,64749568)
    u16* wkrT  = ws + 64749568;              // [128(pad)][2048]        [64749568,65011712)
    u16* wukT  = ws + 65011712;              // [2048][512]             [65011712,66060288)
    u16* wuvT  = ws + 66060288;              // [2048][512]             [66060288,67108864)
    u16* wuqT  = ws + 67108864;              // [2048][1024]            [67108864,69206016)
    u16* wqrT  = ws + 69206016;              // [1024][1024]            [69206016,70254592)
    u16* woutT = ws + 70254592;              // [2048][2048]            [70254592,74448896)

    dim3 blk(256);

    // ---- converts / weight transposes (bf16) ------------------------------
    convert_bf16<<<dim3(8192), blk, 0, stream>>>(x, xb, M * DMODEL);
    transpose_f32_bf16<<<dim3(DCKV / 64, DMODEL / 64), blk, 0, stream>>>(w_dkv, wdkvT, DMODEL, DCKV);
    transpose_f32_bf16<<<dim3(DCQ / 64, DMODEL / 64), blk, 0, stream>>>(w_dq, wdqT, DMODEL, DCQ);
    transpose_f32_bf16<<<dim3(DROPE / 64, DMODEL / 64), blk, 0, stream>>>(w_kr, wkrT, DMODEL, DROPE);
    transpose_f32_bf16<<<dim3(2048 / 64, DCKV / 64), blk, 0, stream>>>(w_uk, wukT, DCKV, 2048);
    transpose_f32_bf16<<<dim3(2048 / 64, DCKV / 64), blk, 0, stream>>>(w_uv, wuvT, DCKV, 2048);
    transpose_f32_bf16<<<dim3(2048 / 64, DCQ / 64), blk, 0, stream>>>(w_uq, wuqT, DCQ, 2048);
    transpose_f32_bf16<<<dim3(1024 / 64, DCQ / 64), blk, 0, stream>>>(w_qr, wqrT, DCQ, 1024);
    transpose_f32_bf16<<<dim3(DMODEL / 64, 2048 / 64), blk, 0, stream>>>(w_out, woutT, 2048, DMODEL);

    // ---- projection GEMMs (plain bf16) ------------------------------------
    gemm_bf16<1><<<dim3(4, 32), blk, 0, stream>>>(xb, wdkvT, ckv, M, DCKV, DMODEL);
    gemm_bf16<1><<<dim3(8, 32), blk, 0, stream>>>(xb, wdqT, cq, M, DCQ, DMODEL);
    gemm_bf16<0><<<dim3(1, 32), blk, 0, stream>>>(xb, wkrT, kr32, M, DROPE, DMODEL);
    gemm_bf16<1><<<dim3(16, 32), blk, 0, stream>>>(ckv, wukT, kc, M, 2048, DCKV);
    gemm_bf16<1><<<dim3(16, 32), blk, 0, stream>>>(ckv, wuvT, vv, M, 2048, DCKV);
    gemm_bf16<1><<<dim3(16, 32), blk, 0, stream>>>(cq, wuqT, qc, M, 2048, DCQ);
    gemm_bf16<0><<<dim3(8, 32), blk, 0, stream>>>(cq, wqrT, qr32, M, NHEAD * DROPE, DCQ);

    // ---- rope (fp32 in, bf16 out) -----------------------------------------
    pope_split<<<dim3(8192), blk, 0, stream>>>(qr32, qrb, delta, NHEAD);
    pope_split<<<dim3(512), blk, 0, stream>>>(kr32, krb, delta, 1);

    // ---- V -> V^T per batch ----------------------------------------------
    transpose_b16<<<dim3(32, 32, BATCH), blk, 0, stream>>>(vv, vt, SEQ, 2048,
                                                           (size_t)SEQ * 2048, (size_t)SEQ * 2048);

    // ---- attention (bf16 out) --------------------------------------------
    attn_mfma<<<dim3(SEQ / 128, BATCH * NHEAD), blk, 0, stream>>>(qc, qrb, kc, krb, vt, ao);

    // ---- output projection (fp32 out) ------------------------------------
    gemm_bf16<0><<<dim3(16, 32), blk, 0, stream>>>(ao, woutT, out, M, DMODEL, 2048);
}